// Round 3
// baseline (354.146 us; speedup 1.0000x reference)
//
#include <hip/hip_runtime.h>
#include <hip/hip_bf16.h>

// Problem constants (fixed by setup_inputs)
#define BB   16      // batches (N_t)
#define NQb  1560    // q rows per batch
#define CC   1024    // channels
#define HH   16      // heads
#define DD   64      // head dim
#define NAk  256     // keys per batch
#define CE   768     // encoder channels
#define MTOT (BB*NQb) // 24960

// 0.125 (D^-0.5) * log2(e): folded into Q-LN so softmax is exp2(s - m)
#define QSCALE 0.18033688011112042f

typedef __attribute__((ext_vector_type(8))) short bf16x8;
typedef __attribute__((ext_vector_type(4))) float f32x4;
typedef unsigned short u16;
typedef unsigned int u32;

__device__ __forceinline__ u16 f2bf(float f) {  // RNE fp32->bf16
  unsigned u = __builtin_bit_cast(unsigned, f);
  u += 0x7FFFu + ((u >> 16) & 1u);
  return (u16)(u >> 16);
}

__device__ __forceinline__ void gl2lds16(const void* g, void* l) {
  __builtin_amdgcn_global_load_lds(
      (const __attribute__((address_space(1))) void*)g,
      (__attribute__((address_space(3))) void*)l, 16, 0, 0);
}

__device__ __forceinline__ f32x4 mfma16(bf16x8 a, bf16x8 b, f32x4 c) {
  return __builtin_amdgcn_mfma_f32_16x16x32_bf16(a, b, c, 0, 0, 0);
}

// ---------------------------------------------------------------------------
// fp32 -> bf16 bulk convert
// ---------------------------------------------------------------------------
__global__ __launch_bounds__(256) void conv_f2b(const float* __restrict__ s,
                                                u16* __restrict__ d, int n4) {
  int i = blockIdx.x * 256 + threadIdx.x;
  if (i >= n4) return;
  float4 v = reinterpret_cast<const float4*>(s)[i];
  ushort4 o;
  o.x = f2bf(v.x); o.y = f2bf(v.y); o.z = f2bf(v.z); o.w = f2bf(v.w);
  reinterpret_cast<ushort4*>(d)[i] = o;
}

// ---------------------------------------------------------------------------
// bf16 MFMA GEMM: out = A[M,KD] @ W[N,KD]^T (+bias, + epilogue)
// 128x128 tile, BK=64, 4 waves (2x2). Grid: x = COL tiles (so consecutive
// workgroups share the A row-panel -> L2 locality), y = ROW tiles.
// EPI: 0 = per-head LN (eps 1e-6), scaled by QSCALE -> bf16 o_bf [M,CC]
//      1 = KV: cols<CC get LN (eps 1e-5) -> Kbf[b][h][na][d];
//              cols>=CC -> Vt[b][h][d][na]  (both bf16)
//      2 = bias -> fp32 o_f [M,CC]
// ---------------------------------------------------------------------------
template <int KD, int EPI>
__global__ __launch_bounds__(256) void gemm_bf16(
    const u16* __restrict__ A, const u16* __restrict__ W,
    const float* __restrict__ bias, const float* __restrict__ lnw,
    const float* __restrict__ lnb, u16* __restrict__ o_bf,
    u16* __restrict__ o_bf2, float* __restrict__ o_f) {
  __shared__ u16 As[128 * 64];
  __shared__ u16 Bs[128 * 64];
  const int tid = threadIdx.x;
  const int l = tid & 63, wid = tid >> 6;
  const int wr = wid >> 1, wc = wid & 1;
  const int row0 = blockIdx.y * 128, col0 = blockIdx.x * 128;

  const int srow = tid >> 3;
  const int scb = ((((tid & 7) * 16) ^ ((srow & 7) << 4)) >> 1);
  const u16* gA = A + (size_t)(row0 + srow) * KD + scb;
  const u16* gB = W + (size_t)(col0 + srow) * KD + scb;
  char* lA = (char*)As + tid * 16;
  char* lB = (char*)Bs + tid * 16;

  int aoff[4][2], boff[4][2];
#pragma unroll
  for (int m = 0; m < 4; ++m)
#pragma unroll
    for (int kk = 0; kk < 2; ++kk) {
      int ra = wr * 64 + m * 16 + (l & 15);
      int rb = wc * 64 + m * 16 + (l & 15);
      int cb = (l >> 4) * 16 + kk * 64;
      aoff[m][kk] = ra * 128 + (cb ^ ((ra & 7) << 4));
      boff[m][kk] = rb * 128 + (cb ^ ((rb & 7) << 4));
    }

  f32x4 acc[4][4];
#pragma unroll
  for (int m = 0; m < 4; ++m)
#pragma unroll
    for (int n = 0; n < 4; ++n) acc[m][n] = (f32x4){0.f, 0.f, 0.f, 0.f};

  for (int k0 = 0; k0 < KD; k0 += 64) {
    __syncthreads();
#pragma unroll
    for (int i = 0; i < 4; ++i) {
      gl2lds16(gA + (size_t)i * 32 * KD + k0, lA + i * 4096);
      gl2lds16(gB + (size_t)i * 32 * KD + k0, lB + i * 4096);
    }
    __syncthreads();
    bf16x8 af[4][2], bfr[4][2];
#pragma unroll
    for (int m = 0; m < 4; ++m)
#pragma unroll
      for (int kk = 0; kk < 2; ++kk) {
        af[m][kk]  = *(const bf16x8*)((const char*)As + aoff[m][kk]);
        bfr[m][kk] = *(const bf16x8*)((const char*)Bs + boff[m][kk]);
      }
#pragma unroll
    for (int kk = 0; kk < 2; ++kk)
#pragma unroll
      for (int m = 0; m < 4; ++m)
#pragma unroll
        for (int n = 0; n < 4; ++n)
          acc[m][n] = mfma16(af[m][kk], bfr[n][kk], acc[m][n]);
  }

  const int colw = col0 + wc * 64;
  float bv[4];
#pragma unroll
  for (int n = 0; n < 4; ++n) bv[n] = bias[colw + n * 16 + (l & 15)];

  if constexpr (EPI == 2) {
#pragma unroll
    for (int m = 0; m < 4; ++m)
#pragma unroll
      for (int reg = 0; reg < 4; ++reg) {
        int grow = row0 + wr * 64 + m * 16 + (l >> 4) * 4 + reg;
#pragma unroll
        for (int n = 0; n < 4; ++n)
          o_f[(size_t)grow * CC + colw + n * 16 + (l & 15)] =
              acc[m][n][reg] + bv[n];
      }
    return;
  }

  if constexpr (EPI == 0) {
    float lwv[4], lbv[4];
#pragma unroll
    for (int n = 0; n < 4; ++n) {
      lwv[n] = lnw[n * 16 + (l & 15)] * QSCALE;
      lbv[n] = lnb[n * 16 + (l & 15)] * QSCALE;
    }
    const int head = colw >> 6;
#pragma unroll
    for (int m = 0; m < 4; ++m)
#pragma unroll
      for (int reg = 0; reg < 4; ++reg) {
        float tv[4], s = 0.f, ss = 0.f;
#pragma unroll
        for (int n = 0; n < 4; ++n) {
          tv[n] = acc[m][n][reg] + bv[n];
          s += tv[n]; ss += tv[n] * tv[n];
        }
#pragma unroll
        for (int off = 1; off < 16; off <<= 1) {
          s  += __shfl_xor(s, off, 16);
          ss += __shfl_xor(ss, off, 16);
        }
        float mean = s * (1.f / 64.f);
        float var  = ss * (1.f / 64.f) - mean * mean;
        float rs   = rsqrtf(var + 1e-6f);
        int grow = row0 + wr * 64 + m * 16 + (l >> 4) * 4 + reg;
        u16* dst = o_bf + (size_t)grow * CC + head * 64;
#pragma unroll
        for (int n = 0; n < 4; ++n)
          dst[n * 16 + (l & 15)] = f2bf((tv[n] - mean) * rs * lwv[n] + lbv[n]);
      }
    return;
  }

  if constexpr (EPI == 1) {
    const bool isK = (colw < CC);
    const int head = (isK ? colw : (colw - CC)) >> 6;
    if (isK) {
      float lwv[4], lbv[4];
#pragma unroll
      for (int n = 0; n < 4; ++n) {
        lwv[n] = lnw[n * 16 + (l & 15)];
        lbv[n] = lnb[n * 16 + (l & 15)];
      }
#pragma unroll
      for (int m = 0; m < 4; ++m)
#pragma unroll
        for (int reg = 0; reg < 4; ++reg) {
          float tv[4], s = 0.f, ss = 0.f;
#pragma unroll
          for (int n = 0; n < 4; ++n) {
            tv[n] = acc[m][n][reg] + bv[n];
            s += tv[n]; ss += tv[n] * tv[n];
          }
#pragma unroll
          for (int off = 1; off < 16; off <<= 1) {
            s  += __shfl_xor(s, off, 16);
            ss += __shfl_xor(ss, off, 16);
          }
          float mean = s * (1.f / 64.f);
          float var  = ss * (1.f / 64.f) - mean * mean;
          float rs   = rsqrtf(var + 1e-5f);
          int grow = row0 + wr * 64 + m * 16 + (l >> 4) * 4 + reg;
          int bb = grow >> 8, na = grow & 255;
          u16* dst = o_bf + (size_t)((bb * HH + head) * NAk + na) * DD;
#pragma unroll
          for (int n = 0; n < 4; ++n)
            dst[n * 16 + (l & 15)] =
                f2bf((tv[n] - mean) * rs * lwv[n] + lbv[n]);
        }
    } else {
#pragma unroll
      for (int m = 0; m < 4; ++m)
#pragma unroll
        for (int reg = 0; reg < 4; ++reg) {
          int grow = row0 + wr * 64 + m * 16 + (l >> 4) * 4 + reg;
          int bb = grow >> 8, na = grow & 255;
          u16* dst = o_bf2 + (size_t)(bb * HH + head) * DD * NAk + na;
#pragma unroll
          for (int n = 0; n < 4; ++n) {
            int d = n * 16 + (l & 15);
            dst[(size_t)d * NAk] = f2bf(acc[m][n][reg] + bv[n]);
          }
        }
    }
    return;
  }
}

// ---------------------------------------------------------------------------
// MFMA attention v3: global-direct fragments (K/V are L2-hot: 64KB/(b,h)),
// swapped QK^T (S^T = K·Q^T) so softmax rows are lane-local (2 shuffles),
// P normalized + packed to per-wave-private swizzled LDS via ds_write_b64,
// single __syncthreads, PV reads P as contiguous b128.
// block = 256 (4 waves x 32 q-rows); grid = (13, HH, BB)
// ---------------------------------------------------------------------------
__global__ __launch_bounds__(256) void attn_mfma(
    const u16* __restrict__ Qbf, const u16* __restrict__ Kbf,
    const u16* __restrict__ Vtbf, u16* __restrict__ Obf) {
  __shared__ u16 P[4][32][256];  // 64KB, per-wave [32 q][256 keys], swizzled
  const int tid = threadIdx.x, l = tid & 63, wid = tid >> 6;
  const int g = l >> 4, ql = l & 15;
  const int qb = blockIdx.x, h = blockIdx.y, b = blockIdx.z;
  const size_t kvbase = (size_t)(b * HH + h) * (NAk * DD);
  const u16* Kp = Kbf + kvbase;
  const u16* Vp = Vtbf + kvbase;
  const int swz = (ql & 7) << 4;  // row-XOR swizzle (row&7 == ql&7)

  // Q fragments (B-operand: col q = m*16+ql, k = d = kk*32 + g*8 + j)
  bf16x8 qf[2][2];
#pragma unroll
  for (int m = 0; m < 2; ++m) {
    int qrow = qb * 128 + wid * 32 + m * 16 + ql;
    int qrc = min(qrow, NQb - 1);
    const u16* p = Qbf + (size_t)(b * NQb + qrc) * CC + h * DD + g * 8;
    qf[m][0] = *(const bf16x8*)(p);
    qf[m][1] = *(const bf16x8*)(p + 32);
  }

  // S^T = K·Q^T: sf[m][n] -> col q = m*16+ql, row key = n*16 + g*4 + reg
  f32x4 sf[2][16];
#pragma unroll
  for (int m = 0; m < 2; ++m)
#pragma unroll
    for (int n = 0; n < 16; ++n) sf[m][n] = (f32x4){0.f, 0.f, 0.f, 0.f};
#pragma unroll
  for (int n = 0; n < 16; ++n) {
    const u16* kp = Kp + (size_t)(n * 16 + ql) * DD + g * 8;
    bf16x8 ka0 = *(const bf16x8*)(kp);
    bf16x8 ka1 = *(const bf16x8*)(kp + 32);
    sf[0][n] = mfma16(ka0, qf[0][0], sf[0][n]);
    sf[0][n] = mfma16(ka1, qf[0][1], sf[0][n]);
    sf[1][n] = mfma16(ka0, qf[1][0], sf[1][n]);
    sf[1][n] = mfma16(ka1, qf[1][1], sf[1][n]);
  }

  // softmax per q (lane-local keys; cross-group via 2 shuffles), exp2 domain
#pragma unroll
  for (int m = 0; m < 2; ++m) {
    float mx = sf[m][0][0];
#pragma unroll
    for (int n = 0; n < 16; ++n)
#pragma unroll
      for (int reg = 0; reg < 4; ++reg) mx = fmaxf(mx, sf[m][n][reg]);
    mx = fmaxf(mx, __shfl_xor(mx, 16));
    mx = fmaxf(mx, __shfl_xor(mx, 32));
    float sum = 0.f;
#pragma unroll
    for (int n = 0; n < 16; ++n)
#pragma unroll
      for (int reg = 0; reg < 4; ++reg) {
        float e = exp2f(sf[m][n][reg] - mx);
        sf[m][n][reg] = e;
        sum += e;
      }
    sum += __shfl_xor(sum, 16);
    sum += __shfl_xor(sum, 32);
    float inv = 1.f / sum;
    // pack normalized P -> per-wave LDS [q][key], swizzled, b64 stores
    char* rowp = (char*)&P[wid][m * 16 + ql][0];
#pragma unroll
    for (int n = 0; n < 16; ++n) {
      u32 lo = (u32)f2bf(sf[m][n][0] * inv) |
               ((u32)f2bf(sf[m][n][1] * inv) << 16);
      u32 hi = (u32)f2bf(sf[m][n][2] * inv) |
               ((u32)f2bf(sf[m][n][3] * inv) << 16);
      *(uint2*)(rowp + ((n * 32 + g * 8) ^ swz)) = make_uint2(lo, hi);
    }
  }
  __syncthreads();  // P visible (per-wave private, but be safe & cheap)

  // O = P · Vt^T : A = P (row q, k = key), B = Vt (col d, k = key)
  f32x4 oacc[2][4];
#pragma unroll
  for (int m = 0; m < 2; ++m)
#pragma unroll
    for (int n = 0; n < 4; ++n) oacc[m][n] = (f32x4){0.f, 0.f, 0.f, 0.f};
#pragma unroll
  for (int ks = 0; ks < 8; ++ks) {
    bf16x8 pa[2], vb[4];
#pragma unroll
    for (int m = 0; m < 2; ++m)
      pa[m] = *(const bf16x8*)((const char*)&P[wid][m * 16 + ql][0] +
                               ((ks * 64 + g * 16) ^ swz));
#pragma unroll
    for (int n = 0; n < 4; ++n)
      vb[n] = *(const bf16x8*)(Vp + (size_t)(n * 16 + ql) * NAk + ks * 32 +
                               g * 8);
#pragma unroll
    for (int m = 0; m < 2; ++m)
#pragma unroll
      for (int n = 0; n < 4; ++n) oacc[m][n] = mfma16(pa[m], vb[n], oacc[m][n]);
  }

  // epilogue: rows q = m*16 + g*4 + reg, cols d = n*16 + ql (already normalized)
#pragma unroll
  for (int m = 0; m < 2; ++m)
#pragma unroll
    for (int reg = 0; reg < 4; ++reg) {
      int qrow = qb * 128 + wid * 32 + m * 16 + g * 4 + reg;
      if (qrow < NQb) {
        u16* dst = Obf + (size_t)(b * NQb + qrow) * CC + h * DD;
#pragma unroll
        for (int n = 0; n < 4; ++n)
          dst[n * 16 + ql] = f2bf(oacc[m][n][reg]);
      }
    }
}

// ---------------------------------------------------------------------------
extern "C" void kernel_launch(void* const* d_in, const int* in_sizes, int n_in,
                              void* d_out, int out_size, void* d_ws,
                              size_t ws_size, hipStream_t stream) {
  const float* x      = (const float*)d_in[0];
  const float* enc    = (const float*)d_in[1];
  const float* q_w    = (const float*)d_in[2];
  const float* q_b    = (const float*)d_in[3];
  const float* kv_w   = (const float*)d_in[4];
  const float* kv_b   = (const float*)d_in[5];
  const float* proj_w = (const float*)d_in[6];
  const float* proj_b = (const float*)d_in[7];
  const float* qn_w   = (const float*)d_in[8];
  const float* qn_b   = (const float*)d_in[9];
  const float* kn_w   = (const float*)d_in[10];
  const float* kn_b   = (const float*)d_in[11];
  float* out = (float*)d_out;

  u16* ws = (u16*)d_ws;
  size_t off = 0;
  u16* Xbf  = ws + off; off += (size_t)MTOT * CC;   // also reused as O
  u16* Qbf  = ws + off; off += (size_t)MTOT * CC;
  u16* Ebf  = ws + off; off += (size_t)BB * NAk * CE;
  u16* QWb  = ws + off; off += (size_t)CC * CC;
  u16* KVWb = ws + off; off += (size_t)2 * CC * CE;
  u16* PWb  = ws + off; off += (size_t)CC * CC;
  u16* Kbf  = ws + off; off += (size_t)BB * HH * NAk * DD;
  u16* Vtbf = ws + off; off += (size_t)BB * HH * NAk * DD;

  auto cvt = [&](const float* s, u16* d, size_t n) {
    int n4 = (int)(n / 4);
    conv_f2b<<<(n4 + 255) / 256, 256, 0, stream>>>(s, d, n4);
  };
  cvt(x, Xbf, (size_t)MTOT * CC);
  cvt(enc, Ebf, (size_t)BB * NAk * CE);
  cvt(q_w, QWb, (size_t)CC * CC);
  cvt(kv_w, KVWb, (size_t)2 * CC * CE);
  cvt(proj_w, PWb, (size_t)CC * CC);

  // grid.x = col tiles (consecutive wgs share the A row-panel)
  gemm_bf16<CC, 0><<<dim3(CC / 128, MTOT / 128), 256, 0, stream>>>(
      Xbf, QWb, q_b, qn_w, qn_b, Qbf, nullptr, nullptr);
  gemm_bf16<CE, 1><<<dim3((2 * CC) / 128, (BB * NAk) / 128), 256, 0, stream>>>(
      Ebf, KVWb, kv_b, kn_w, kn_b, Kbf, Vtbf, nullptr);
  attn_mfma<<<dim3((NQb + 127) / 128, HH, BB), 256, 0, stream>>>(Qbf, Kbf,
                                                                 Vtbf, Xbf);
  gemm_bf16<CC, 2><<<dim3(CC / 128, MTOT / 128), 256, 0, stream>>>(
      Xbf, PWb, proj_b, nullptr, nullptr, nullptr, nullptr, out);
}